// Round 7
// baseline (603.310 us; speedup 1.0000x reference)
//
#include <hip/hip_runtime.h>
#include <cfloat>

#define NV    1024
#define CDIM  256
#define NROWS 131072
#define TOTAL 33554432
#define HW    4096
// 1-MFMA prune window: dot-error sigma ~3.4e-5 (xl*e + xh*el cross terms),
// need |e1-e2| <= WWIN - np_swing(6.5e-5): 2.85e-4 ~ 5.9 sigma of sqrt(2)*3.4e-5.
#define WWIN  3.5e-4f
#define MST   68           // merge LDS stride (floats): conflict-free b128

typedef __attribute__((ext_vector_type(8))) short bf16x8;
typedef __attribute__((ext_vector_type(4))) float f32x4;

// ---------------------------------------------------------------------------
// numpy fp32 pairwise sum of 256 terms (AVX512 base case) — bitwise replica.
// ---------------------------------------------------------------------------
template <typename GET>
__device__ __forceinline__ float np_s128(const GET& get, int base) {
    float tv[16];
#pragma unroll
    for (int l = 0; l < 16; ++l) {
        float s0 = __fadd_rn(get(base + l),      get(base + 64 + l));
        float s1 = __fadd_rn(get(base + 16 + l), get(base + 80 + l));
        float s2 = __fadd_rn(get(base + 32 + l), get(base + 96 + l));
        float s3 = __fadd_rn(get(base + 48 + l), get(base + 112 + l));
        tv[l] = __fadd_rn(__fadd_rn(s0, s1), __fadd_rn(s2, s3));
    }
    float u[8];
#pragma unroll
    for (int l = 0; l < 8; ++l) u[l] = __fadd_rn(tv[l], tv[l + 8]);
    float v[4];
#pragma unroll
    for (int l = 0; l < 4; ++l) v[l] = __fadd_rn(u[l], u[l + 4]);
    return __fadd_rn(__fadd_rn(v[0], v[2]), __fadd_rn(v[1], v[3]));
}
template <typename GET>
__device__ __forceinline__ float np_s256(const GET& get) {
    return __fadd_rn(np_s128(get, 0), np_s128(get, 128));
}

__device__ __forceinline__ unsigned short f2bf_rne(float f) {
    unsigned u = __float_as_uint(f);
    unsigned r = u + 0x7fffu + ((u >> 16) & 1u);
    return (unsigned short)(r >> 16);
}

// exact np-fp32 distance: d = fl( fl(sx+se) - fl(2 * seqFMA(x,e)) )
__device__ __forceinline__ float exact_d(const float* __restrict__ xrow,
                                         const float* __restrict__ erow,
                                         float sxn, float se) {
    float g = 0.f;
    for (int c = 0; c < CDIM; ++c) g = __fmaf_rn(xrow[c], erow[c], g);
    return __fsub_rn(__fadd_rn(sxn, se), __fmul_rn(2.0f, g));
}

__global__ void zero_hdr(double* loss, int* fbcnt) {
    if (threadIdx.x == 0) { *loss = 0.0; *fbcnt = 0; }
}

__global__ void enorm_kernel(const float* __restrict__ emb, float* __restrict__ enf) {
    int k = blockIdx.x * blockDim.x + threadIdx.x;
    if (k < NV) {
        const float* e = emb + (size_t)k * CDIM;
        auto get = [e](int c) { return __fmul_rn(e[c], e[c]); };
        enf[k] = np_s256(get);
    }
}

// emb -> bf16 hi only (RNE).
__global__ void esplit_kernel(const float* __restrict__ emb,
                              unsigned short* __restrict__ ehg) {
    int i = blockIdx.x * blockDim.x + threadIdx.x;
    if (i < NV * CDIM) ehg[i] = f2bf_rne(emb[i]);
}

// ---------------------------------------------------------------------------
// MFMA argmin: block 256 thr (4 waves, 2x2), M-tile 64 rows, N chunks of 32.
// Round-7: NO B staging, NO main-loop barriers. ehg is 512KB -> L2-resident
// per XCD; each lane reads its B fragment directly from global. A wave's
// b128 B-load = 16 x 64B contiguous segments (4 quads cover 64B of one row)
// = clean L2-line granularity. Waves run barrier-free; L2 latency hides
// under cross-wave TLP (LDS 30KB -> 5 blocks/CU). z values bitwise identical
// to the staged version (same address math, same MFMA order).
// ---------------------------------------------------------------------------
__global__ __launch_bounds__(256, 2) void gemm_argmin_kernel(
        const float* __restrict__ x, const float* __restrict__ emb,
        const unsigned short* __restrict__ ehg,
        const float* __restrict__ enf, int* __restrict__ idx,
        int* __restrict__ fb_list, int* __restrict__ fb_cnt) {
    __shared__ __align__(16) char sbuf[26112];   // merge buffers only
    __shared__ __align__(16) float senf[NV];     // 4 KB e-norm cache

    const int tid  = threadIdx.x;
    const int lane = tid & 63;
    const int lcol = lane & 15;
    const int quad = lane >> 4;
    const int wid  = tid >> 6;
    const int wy   = wid >> 1;               // m-half
    const int wx   = wid & 1;                // n-half
    const int mbase = wy * 32;
    const int nl   = wx * 16 + lcol;         // code-col position within 32-chunk

    const int rowbase = blockIdx.x * 64;
    const int b   = rowbase >> 12;
    const int hw0 = rowbase & 4095;
    const float* xb = x + ((size_t)b * CDIM) * HW + hw0;

    // stage e-norms into LDS
    *(float4*)&senf[tid * 4] = *(const float4*)&enf[tid * 4];

    // ---- build A (xh) fragments straight from global ----
    // lane (lcol,quad): row m = mbase+t*16+lcol (16 consecutive rows per quad
    // -> 64B coalesced lines), channels c0..c0+7 per kc.
    bf16x8 ah[2][8];
#pragma unroll
    for (int t = 0; t < 2; ++t) {
        const int m = mbase + t * 16 + lcol;
#pragma unroll
        for (int kc = 0; kc < 8; ++kc) {
            const int c0 = kc * 32 + quad * 8;
            float fv[8];
#pragma unroll
            for (int j = 0; j < 8; ++j) fv[j] = xb[(size_t)(c0 + j) * HW + m];
#pragma unroll
            for (int j = 0; j < 8; ++j) ah[t][kc][j] = (short)f2bf_rne(fv[j]);
        }
    }

    // ---- per-lane min tracking: 8 slots (2 mtiles x 4 regs) ----
    // i1 packed: 8-bit chunk-id fields in 2 regs (k = ch*32 + nl), static idx.
    float m1[8], m2[8];
#pragma unroll
    for (int s = 0; s < 8; ++s) { m1[s] = FLT_MAX; m2[s] = FLT_MAX; }
    unsigned i1p[2] = { 0xffffffffu, 0xffffffffu };

    __syncthreads();   // senf visible (only barrier before merge)

    // B fragment source: row k0+nl, elems (kc*4+quad)*8 .. +8
    const unsigned short* bp = ehg + (size_t)nl * 256 + quad * 8;

#pragma unroll 1
    for (int ch = 0; ch < 32; ++ch) {
        const float enfv = senf[ch * 32 + nl];
        f32x4 acc[2];
        acc[0] = (f32x4){0.f, 0.f, 0.f, 0.f};
        acc[1] = (f32x4){0.f, 0.f, 0.f, 0.f};

#pragma unroll
        for (int kc = 0; kc < 8; ++kc) {
            const bf16x8 bh = *(const bf16x8*)(bp + kc * 32);
            acc[0] = __builtin_amdgcn_mfma_f32_16x16x32_bf16(
                ah[0][kc], bh, acc[0], 0, 0, 0);
            acc[1] = __builtin_amdgcn_mfma_f32_16x16x32_bf16(
                ah[1][kc], bh, acc[1], 0, 0, 0);
        }
        bp += 32 * 256;   // next 32 codebook rows

        // chunk epilogue: z~ = enf - 2*acc; branchless min1/min2 per slot.
        // m2' = med3(z,m1,m2), m1' = min(z,m1) == if/else-if form (NaN-free).
#pragma unroll
        for (int t = 0; t < 2; ++t)
#pragma unroll
            for (int r = 0; r < 4; ++r) {
                const float z = __fmaf_rn(-2.0f, acc[t][r], enfv);
                const int s  = t * 4 + r;
                const int sh = r * 8;
                const bool lt1 = z < m1[s];
                m2[s] = __builtin_amdgcn_fmed3f(z, m1[s], m2[s]);
                m1[s] = fminf(z, m1[s]);
                const unsigned cand = (i1p[t] & ~(0xffu << sh)) | ((unsigned)ch << sh);
                i1p[t] = lt1 ? cand : i1p[t];
            }
    }

    // ---- merge: stride-68, vector writes (conflict-free b128 both sides) ----
    float* Mv1 = (float*)sbuf;               // 32*68*4 = 8704 B
    int*   Mi1 = (int*)(sbuf + 8704);        // 8704 B
    float* Mv2 = (float*)(sbuf + 17408);     // 8704 B  (total 26112)
#pragma unroll
    for (int t = 0; t < 2; ++t) {
        const int row0 = mbase + t * 16 + quad * 4;
        const int base = nl * MST + row0;
        *(float4*)&Mv1[base] = *(const float4*)&m1[t * 4];
        *(float4*)&Mv2[base] = *(const float4*)&m2[t * 4];
        int4 kk;
        kk.x = (int)((i1p[t] >>  0) & 0xffu) * 32 + nl;
        kk.y = (int)((i1p[t] >>  8) & 0xffu) * 32 + nl;
        kk.z = (int)((i1p[t] >> 16) & 0xffu) * 32 + nl;
        kk.w = (int)((i1p[t] >> 24) & 0xffu) * 32 + nl;
        *(int4*)&Mi1[base] = kk;
    }
    __syncthreads();

    if (tid < 64) {
        const int row = tid;
        float M = FLT_MAX;
#pragma unroll
        for (int c = 0; c < 32; ++c) M = fminf(M, Mv1[c * MST + row]);
        const float lim = M + WWIN;

        int cand[12]; int cnt = 0; bool overflow = false;
        for (int c = 0; c < 32; ++c) {
            if (Mv2[c * MST + row] <= lim) overflow = true;   // hidden 2nd in col
            if (Mv1[c * MST + row] <= lim) {
                if (cnt < 12) cand[cnt++] = Mi1[c * MST + row] & (NV - 1);
                else overflow = true;
            }
        }
        if (overflow) {
            const int pos = atomicAdd(fb_cnt, 1);
            fb_list[pos] = rowbase + row;
        } else if (cnt == 1) {
            idx[rowbase + row] = cand[0];
        } else {
            // exact np-fp32 re-eval; x row read from global (L3/L1-hot,
            // bitwise identical to values used for the fragments).
            auto g2 = [xb, row](int c) {
                const float v = xb[(size_t)c * HW + row];
                return __fmul_rn(v, v);
            };
            const float sxn = np_s256(g2);
            float bd = FLT_MAX; int bk = 0x7fffffff;
            for (int cc = 0; cc < cnt; ++cc) {
                const int kk = cand[cc];
                const float* er = emb + (size_t)kk * CDIM;
                float gacc = 0.f;
                for (int c2 = 0; c2 < CDIM; ++c2)
                    gacc = __fmaf_rn(xb[(size_t)c2 * HW + row], er[c2], gacc);
                const float d = __fsub_rn(__fadd_rn(sxn, senf[kk]),
                                          __fmul_rn(2.0f, gacc));
                if (d < bd || (d == bd && kk < bk)) { bd = d; bk = kk; }
            }
            idx[rowbase + row] = bk;
        }
    }
}

// full exact scan for rare ambiguous rows: one block per row.
__global__ __launch_bounds__(256) void fallback_kernel(
        const float* __restrict__ x, const float* __restrict__ emb,
        const float* __restrict__ enf, int* __restrict__ idx,
        const int* __restrict__ fb_list, const int* __restrict__ fb_cnt) {
    __shared__ float sxr[CDIM];
    __shared__ float rv[256];
    __shared__ int   rk[256];

    const int n = *fb_cnt;
    for (int i = blockIdx.x; i < n; i += gridDim.x) {
        const int r  = fb_list[i];
        const int b  = r >> 12;
        const int hw = r & 4095;
        sxr[threadIdx.x] = x[((size_t)(b * CDIM + threadIdx.x)) * HW + hw];
        __syncthreads();

        auto get = [](int c) { float v = ((const float*)sxr)[c]; return __fmul_rn(v, v); };
        float sxn = np_s256(get);

        float bd = FLT_MAX; int bk = 0x7fffffff;
#pragma unroll
        for (int j = 0; j < 4; ++j) {
            const int k = threadIdx.x * 4 + j;
            float d = exact_d(sxr, emb + (size_t)k * CDIM, sxn, enf[k]);
            if (d < bd) { bd = d; bk = k; }    // ascending k per thread
        }
        rv[threadIdx.x] = bd; rk[threadIdx.x] = bk;
        __syncthreads();
        for (int sft = 128; sft > 0; sft >>= 1) {
            if (threadIdx.x < sft) {
                float ov = rv[threadIdx.x + sft]; int ok = rk[threadIdx.x + sft];
                if (ov < rv[threadIdx.x] ||
                    (ov == rv[threadIdx.x] && ok < rk[threadIdx.x])) {
                    rv[threadIdx.x] = ov; rk[threadIdx.x] = ok;
                }
            }
            __syncthreads();
        }
        if (threadIdx.x == 0) idx[r] = rk[0];
        __syncthreads();
    }
}

// coalesced gather: block = 64 rows; stage emb[idx] rows in LDS, write [c][hw].
// Also emits the float idx output (idxout fused here).
__global__ __launch_bounds__(256) void gather_kernel(
        const float* __restrict__ x, const float* __restrict__ emb,
        const int* __restrict__ idx, float* __restrict__ out,
        float* __restrict__ oidx, double* __restrict__ loss) {
    __shared__ float sE[64][260];
    __shared__ int   sidx[64];
    __shared__ double red[256];

    const int tid = threadIdx.x;
    const int rowbase = blockIdx.x * 64;
    const int b   = rowbase >> 12;
    const int hw0 = rowbase & 4095;

    if (tid < 64) sidx[tid] = idx[rowbase + tid];
    __syncthreads();

    if (tid < 64) oidx[rowbase + tid] = (float)sidx[tid];

    {
        const int r  = tid >> 2;
        const int qt = tid & 3;
        const float* e = emb + (size_t)sidx[r] * CDIM + qt * 64;
        for (int u = 0; u < 16; ++u) {
            float4 v = *(const float4*)(e + u * 4);
            *(float4*)&sE[r][qt * 64 + u * 4] = v;
        }
    }
    __syncthreads();

    const float* xb = x + ((size_t)b * CDIM) * HW + hw0;
    float* ob = out + ((size_t)b * CDIM) * HW + hw0;
    double s = 0.0;
    for (int it = 0; it < 16; ++it) {
        int c  = it * 16 + (tid >> 4);
        int m4 = (tid & 15) * 4;
        float4 ev;
        ev.x = sE[m4 + 0][c]; ev.y = sE[m4 + 1][c];
        ev.z = sE[m4 + 2][c]; ev.w = sE[m4 + 3][c];
        float4 xv = *(const float4*)(xb + (size_t)c * HW + m4);
        *(float4*)(ob + (size_t)c * HW + m4) = ev;
        float d0 = ev.x - xv.x, d1 = ev.y - xv.y, d2 = ev.z - xv.z, d3 = ev.w - xv.w;
        s = fma((double)d0, (double)d0, s);
        s = fma((double)d1, (double)d1, s);
        s = fma((double)d2, (double)d2, s);
        s = fma((double)d3, (double)d3, s);
    }
    red[tid] = s;
    __syncthreads();
    for (int sft = 128; sft > 0; sft >>= 1) {
        if (tid < sft) red[tid] += red[tid + sft];
        __syncthreads();
    }
    if (tid == 0) atomicAdd(loss, red[0]);
}

__global__ void fin_kernel(const double* __restrict__ loss, float* __restrict__ o) {
    *o = (float)(1.25 * (*loss) / (double)TOTAL);
}

extern "C" void kernel_launch(void* const* d_in, const int* in_sizes, int n_in,
                              void* d_out, int out_size, void* d_ws, size_t ws_size,
                              hipStream_t stream) {
    const float* x   = (const float*)d_in[0];
    const float* emb = (const float*)d_in[1];
    float* out = (float*)d_out;
    char*  ws  = (char*)d_ws;

    double* loss    = (double*)ws;
    int*    fb_cnt  = (int*)(ws + 8);
    float*  enf     = (float*)(ws + 64);
    int*    idx     = (int*)(ws + 64 + 4096);
    int*    fb_list = idx + NROWS;

    unsigned short* ehg = (unsigned short*)d_out;   // scratch, overwritten by gather

    float* out_xq   = out;
    float* out_idx  = out + (size_t)TOTAL;
    float* out_loss = out + (size_t)TOTAL + NROWS;

    hipLaunchKernelGGL(zero_hdr,         dim3(1),            dim3(64),  0, stream, loss, fb_cnt);
    hipLaunchKernelGGL(enorm_kernel,     dim3(4),            dim3(256), 0, stream, emb, enf);
    hipLaunchKernelGGL(esplit_kernel,    dim3(NV * CDIM / 256), dim3(256), 0, stream, emb, ehg);
    hipLaunchKernelGGL(gemm_argmin_kernel, dim3(NROWS / 64), dim3(256), 0, stream,
                       x, emb, ehg, enf, idx, fb_list, fb_cnt);
    hipLaunchKernelGGL(fallback_kernel,  dim3(256),          dim3(256), 0, stream,
                       x, emb, enf, idx, fb_list, fb_cnt);
    hipLaunchKernelGGL(gather_kernel,    dim3(NROWS / 64),   dim3(256), 0, stream,
                       x, emb, idx, out_xq, out_idx, loss);
    hipLaunchKernelGGL(fin_kernel,       dim3(1),            dim3(1),   0, stream, loss, out_loss);
}

// Round 8
// 445.522 us; speedup vs baseline: 1.3542x; 1.3542x over previous
//
#include <hip/hip_runtime.h>
#include <cfloat>

#define NV    1024
#define CDIM  256
#define NROWS 131072
#define TOTAL 33554432
#define HW    4096
// 1-MFMA prune window: dot-error sigma ~3.4e-5 (xl*e + xh*el cross terms),
// need |e1-e2| <= WWIN - np_swing(6.5e-5): 2.85e-4 ~ 5.9 sigma of sqrt(2)*3.4e-5.
#define WWIN  3.5e-4f
#define MST   68           // merge LDS stride (floats): conflict-free b128
#define EST   261          // gather sE stride: 4*261 % 32 = 20 -> 8 banks, 2-way (free)

typedef __attribute__((ext_vector_type(8))) short bf16x8;
typedef __attribute__((ext_vector_type(4))) float f32x4;

// ---------------------------------------------------------------------------
// numpy fp32 pairwise sum of 256 terms (AVX512 base case) — bitwise replica.
// ---------------------------------------------------------------------------
template <typename GET>
__device__ __forceinline__ float np_s128(const GET& get, int base) {
    float tv[16];
#pragma unroll
    for (int l = 0; l < 16; ++l) {
        float s0 = __fadd_rn(get(base + l),      get(base + 64 + l));
        float s1 = __fadd_rn(get(base + 16 + l), get(base + 80 + l));
        float s2 = __fadd_rn(get(base + 32 + l), get(base + 96 + l));
        float s3 = __fadd_rn(get(base + 48 + l), get(base + 112 + l));
        tv[l] = __fadd_rn(__fadd_rn(s0, s1), __fadd_rn(s2, s3));
    }
    float u[8];
#pragma unroll
    for (int l = 0; l < 8; ++l) u[l] = __fadd_rn(tv[l], tv[l + 8]);
    float v[4];
#pragma unroll
    for (int l = 0; l < 4; ++l) v[l] = __fadd_rn(u[l], u[l + 4]);
    return __fadd_rn(__fadd_rn(v[0], v[2]), __fadd_rn(v[1], v[3]));
}
template <typename GET>
__device__ __forceinline__ float np_s256(const GET& get) {
    return __fadd_rn(np_s128(get, 0), np_s128(get, 128));
}

__device__ __forceinline__ unsigned short f2bf_rne(float f) {
    unsigned u = __float_as_uint(f);
    unsigned r = u + 0x7fffu + ((u >> 16) & 1u);
    return (unsigned short)(r >> 16);
}

// exact np-fp32 distance: d = fl( fl(sx+se) - fl(2 * seqFMA(x,e)) )
__device__ __forceinline__ float exact_d(const float* __restrict__ xrow,
                                         const float* __restrict__ erow,
                                         float sxn, float se) {
    float g = 0.f;
    for (int c = 0; c < CDIM; ++c) g = __fmaf_rn(xrow[c], erow[c], g);
    return __fsub_rn(__fadd_rn(sxn, se), __fmul_rn(2.0f, g));
}

// async global->LDS, 16B per lane, linear LDS dest (wave base + lane*16)
__device__ __forceinline__ void gload_lds16(const void* gsrc, void* ldst) {
    __builtin_amdgcn_global_load_lds(
        (const __attribute__((address_space(1))) void*)gsrc,
        (__attribute__((address_space(3))) void*)ldst, 16, 0, 0);
}

// ---------------------------------------------------------------------------
// prep: fuses zero_hdr + esplit (emb -> bf16 hi) + enorm (np-fp32 ||e||^2).
// block k = emb row k (256 elems, 1 per thread).
// ---------------------------------------------------------------------------
__global__ __launch_bounds__(256) void prep_kernel(
        const float* __restrict__ emb, unsigned short* __restrict__ ehg,
        float* __restrict__ enf, double* loss, int* fbcnt) {
    __shared__ float sq[CDIM];
    const int k = blockIdx.x, c = threadIdx.x;
    if (k == 0 && c == 0) { *loss = 0.0; *fbcnt = 0; }
    const float e = emb[(size_t)k * CDIM + c];
    ehg[(size_t)k * CDIM + c] = f2bf_rne(e);
    sq[c] = __fmul_rn(e, e);
    __syncthreads();
    if (c == 0) {
        auto get = [](int i) { return ((const float*)sq)[i]; };
        enf[k] = np_s256(get);
    }
}

// ---------------------------------------------------------------------------
// MFMA argmin: block 256 thr (4 waves, 2x2), M-tile 64 rows, N chunks of 32.
// Round-8: round-6 structure restored (double-buffered LDS staging via
// global_load_lds, STAGE(next) issued before compute, one barrier/chunk —
// measured 225us; round-7's barrier-free direct-L2 B-reads regressed to 351:
// demand L2 latency with no prefetch beats no-barrier + occupancy).
// Change vs round 6: senf LDS dropped — enf is 4KB, L1-resident; read direct.
// LDS = exactly 32KB -> 5 blocks/CU (was 36.9KB -> 4).
// ---------------------------------------------------------------------------
__global__ __launch_bounds__(256, 2) void gemm_argmin_kernel(
        const float* __restrict__ x, const float* __restrict__ emb,
        const unsigned short* __restrict__ ehg,
        const float* __restrict__ enf, int* __restrict__ idx,
        int* __restrict__ fb_list, int* __restrict__ fb_cnt) {
    __shared__ __align__(16) char sbuf[32768];   // 2 x 16KB eh chunk dbuf

    const int tid  = threadIdx.x;
    const int lane = tid & 63;
    const int lcol = lane & 15;
    const int quad = lane >> 4;
    const int wid  = tid >> 6;
    const int wy   = wid >> 1;               // m-half
    const int wx   = wid & 1;                // n-half
    const int mbase = wy * 32;
    const int nl   = wx * 16 + lcol;         // code-col position within 32-chunk

    const int rowbase = blockIdx.x * 64;
    const int b   = rowbase >> 12;
    const int hw0 = rowbase & 4095;
    const float* xb = x + ((size_t)b * CDIM) * HW + hw0;

    // stage eh chunk `ch` into buffer `buf`: linear LDS granule g holds global
    // granule (n = g>>5, s5 = (p-n)&31) so read-side swizzle is unchanged.
    auto STAGE = [&](int buf, int ch) {
        char* dB = sbuf + (buf << 14);
        const int k0 = ch * 32;
#pragma unroll
        for (int it = 0; it < 4; ++it) {
            const int g  = it * 256 + tid;
            const int n  = g >> 5, p = g & 31;
            const int s5 = (p - n) & 31;
            const size_t src = (size_t)(k0 + n) * 256 + s5 * 8;
            gload_lds16(ehg + src, dB + g * 16);
        }
    };

    // prologue: kick off chunk-0 staging; latency hides under fragment build.
    STAGE(0, 0);

    // ---- build A (xh) fragments straight from global ----
    // lane (lcol,quad): row m = mbase+t*16+lcol (16 consecutive rows per quad
    // -> 64B coalesced lines), channels c0..c0+7 per kc.
    bf16x8 ah[2][8];
#pragma unroll
    for (int t = 0; t < 2; ++t) {
        const int m = mbase + t * 16 + lcol;
#pragma unroll
        for (int kc = 0; kc < 8; ++kc) {
            const int c0 = kc * 32 + quad * 8;
            float fv[8];
#pragma unroll
            for (int j = 0; j < 8; ++j) fv[j] = xb[(size_t)(c0 + j) * HW + m];
#pragma unroll
            for (int j = 0; j < 8; ++j) ah[t][kc][j] = (short)f2bf_rne(fv[j]);
        }
    }

    // ---- per-lane min tracking: 8 slots (2 mtiles x 4 regs) ----
    // i1 packed: 8-bit chunk-id fields in 2 regs (k = ch*32 + nl), static idx.
    float m1[8], m2[8];
#pragma unroll
    for (int s = 0; s < 8; ++s) { m1[s] = FLT_MAX; m2[s] = FLT_MAX; }
    unsigned i1p[2] = { 0xffffffffu, 0xffffffffu };

    __syncthreads();   // chunk-0 staged (syncthreads drains vmcnt)

    int cur = 0;
    for (int ch = 0; ch < 32; ++ch) {
        // issue next chunk's staging into the other buffer BEFORE compute;
        // all waves finished reading that buffer at the previous barrier.
        if (ch < 31) STAGE(cur ^ 1, ch + 1);

        const unsigned short* sBh = (const unsigned short*)(sbuf + (cur << 14));

        const float enfv = enf[ch * 32 + nl];   // 4KB table, L1-hot
        f32x4 acc[2];
        acc[0] = (f32x4){0.f, 0.f, 0.f, 0.f};
        acc[1] = (f32x4){0.f, 0.f, 0.f, 0.f};

#pragma unroll
        for (int kc = 0; kc < 8; ++kc) {
            const int s5  = kc * 4 + quad;
            const int off = nl * 256 + (((s5 + nl) & 31) * 8);
            const bf16x8 bh = *(const bf16x8*)&sBh[off];
#pragma unroll
            for (int t = 0; t < 2; ++t)
                acc[t] = __builtin_amdgcn_mfma_f32_16x16x32_bf16(
                    ah[t][kc], bh, acc[t], 0, 0, 0);
        }

        // chunk epilogue: z~ = enf - 2*acc; branchless min1/min2 per slot.
        // m2' = med3(z,m1,m2), m1' = min(z,m1) == if/else-if form (NaN-free).
#pragma unroll
        for (int t = 0; t < 2; ++t)
#pragma unroll
            for (int r = 0; r < 4; ++r) {
                const float z = __fmaf_rn(-2.0f, acc[t][r], enfv);
                const int s  = t * 4 + r;
                const int sh = r * 8;
                const bool lt1 = z < m1[s];
                m2[s] = __builtin_amdgcn_fmed3f(z, m1[s], m2[s]);
                m1[s] = fminf(z, m1[s]);
                const unsigned cand = (i1p[t] & ~(0xffu << sh)) | ((unsigned)ch << sh);
                i1p[t] = lt1 ? cand : i1p[t];
            }

        // one barrier per chunk: drains my staging loads (vmcnt) + ds_reads.
        __syncthreads();
        cur ^= 1;
    }

    // ---- merge: stride-68, vector writes (conflict-free b128 both sides) ----
    float* Mv1 = (float*)sbuf;               // 32*68*4 = 8704 B
    int*   Mi1 = (int*)(sbuf + 8704);        // 8704 B
    float* Mv2 = (float*)(sbuf + 17408);     // 8704 B  (total 26112 <= 32768)
#pragma unroll
    for (int t = 0; t < 2; ++t) {
        const int row0 = mbase + t * 16 + quad * 4;
        const int base = nl * MST + row0;
        *(float4*)&Mv1[base] = *(const float4*)&m1[t * 4];
        *(float4*)&Mv2[base] = *(const float4*)&m2[t * 4];
        int4 kk;
        kk.x = (int)((i1p[t] >>  0) & 0xffu) * 32 + nl;
        kk.y = (int)((i1p[t] >>  8) & 0xffu) * 32 + nl;
        kk.z = (int)((i1p[t] >> 16) & 0xffu) * 32 + nl;
        kk.w = (int)((i1p[t] >> 24) & 0xffu) * 32 + nl;
        *(int4*)&Mi1[base] = kk;
    }
    __syncthreads();

    if (tid < 64) {
        const int row = tid;
        float M = FLT_MAX;
#pragma unroll
        for (int c = 0; c < 32; ++c) M = fminf(M, Mv1[c * MST + row]);
        const float lim = M + WWIN;

        int cand[12]; int cnt = 0; bool overflow = false;
        for (int c = 0; c < 32; ++c) {
            if (Mv2[c * MST + row] <= lim) overflow = true;   // hidden 2nd in col
            if (Mv1[c * MST + row] <= lim) {
                if (cnt < 12) cand[cnt++] = Mi1[c * MST + row] & (NV - 1);
                else overflow = true;
            }
        }
        if (overflow) {
            const int pos = atomicAdd(fb_cnt, 1);
            fb_list[pos] = rowbase + row;
        } else if (cnt == 1) {
            idx[rowbase + row] = cand[0];
        } else {
            // exact np-fp32 re-eval; x row read from global (L3/L1-hot,
            // bitwise identical to values used for the fragments).
            auto g2 = [xb, row](int c) {
                const float v = xb[(size_t)c * HW + row];
                return __fmul_rn(v, v);
            };
            const float sxn = np_s256(g2);
            float bd = FLT_MAX; int bk = 0x7fffffff;
            for (int cc = 0; cc < cnt; ++cc) {
                const int kk = cand[cc];
                const float* er = emb + (size_t)kk * CDIM;
                float gacc = 0.f;
                for (int c2 = 0; c2 < CDIM; ++c2)
                    gacc = __fmaf_rn(xb[(size_t)c2 * HW + row], er[c2], gacc);
                const float d = __fsub_rn(__fadd_rn(sxn, enf[kk]),
                                          __fmul_rn(2.0f, gacc));
                if (d < bd || (d == bd && kk < bk)) { bd = d; bk = kk; }
            }
            idx[rowbase + row] = bk;
        }
    }
}

// full exact scan for rare ambiguous rows: one block per row.
__global__ __launch_bounds__(256) void fallback_kernel(
        const float* __restrict__ x, const float* __restrict__ emb,
        const float* __restrict__ enf, int* __restrict__ idx,
        const int* __restrict__ fb_list, const int* __restrict__ fb_cnt) {
    __shared__ float sxr[CDIM];
    __shared__ float rv[256];
    __shared__ int   rk[256];

    const int n = *fb_cnt;
    for (int i = blockIdx.x; i < n; i += gridDim.x) {
        const int r  = fb_list[i];
        const int b  = r >> 12;
        const int hw = r & 4095;
        sxr[threadIdx.x] = x[((size_t)(b * CDIM + threadIdx.x)) * HW + hw];
        __syncthreads();

        auto get = [](int c) { float v = ((const float*)sxr)[c]; return __fmul_rn(v, v); };
        float sxn = np_s256(get);

        float bd = FLT_MAX; int bk = 0x7fffffff;
#pragma unroll
        for (int j = 0; j < 4; ++j) {
            const int k = threadIdx.x * 4 + j;
            float d = exact_d(sxr, emb + (size_t)k * CDIM, sxn, enf[k]);
            if (d < bd) { bd = d; bk = k; }    // ascending k per thread
        }
        rv[threadIdx.x] = bd; rk[threadIdx.x] = bk;
        __syncthreads();
        for (int sft = 128; sft > 0; sft >>= 1) {
            if (threadIdx.x < sft) {
                float ov = rv[threadIdx.x + sft]; int ok = rk[threadIdx.x + sft];
                if (ov < rv[threadIdx.x] ||
                    (ov == rv[threadIdx.x] && ok < rk[threadIdx.x])) {
                    rv[threadIdx.x] = ov; rk[threadIdx.x] = ok;
                }
            }
            __syncthreads();
        }
        if (threadIdx.x == 0) idx[r] = rk[0];
        __syncthreads();
    }
}

// coalesced gather: block = 64 rows; stage emb[idx] rows in LDS, write [c][hw].
// Round-8: sE stride 260 -> 261. At stride 260 the transpose-read
// sE[(tid&15)*4+i][c] had 16 lanes on 2 banks (8-way conflict) x 64 reads
// per thread (~150us est); stride 261 -> 8 banks, 2 lanes/bank = free.
// Also emits the float idx output (idxout fused here).
__global__ __launch_bounds__(256) void gather_kernel(
        const float* __restrict__ x, const float* __restrict__ emb,
        const int* __restrict__ idx, float* __restrict__ out,
        float* __restrict__ oidx, double* __restrict__ loss) {
    __shared__ float sE[64][EST];
    __shared__ int   sidx[64];
    __shared__ double red[256];

    const int tid = threadIdx.x;
    const int rowbase = blockIdx.x * 64;
    const int b   = rowbase >> 12;
    const int hw0 = rowbase & 4095;

    if (tid < 64) sidx[tid] = idx[rowbase + tid];
    __syncthreads();

    if (tid < 64) oidx[rowbase + tid] = (float)sidx[tid];

    {
        const int r  = tid >> 2;
        const int qt = tid & 3;
        const float* e = emb + (size_t)sidx[r] * CDIM + qt * 64;
        for (int u = 0; u < 16; ++u) {
            float4 v = *(const float4*)(e + u * 4);
            *(float4*)&sE[r][qt * 64 + u * 4] = v;
        }
    }
    __syncthreads();

    const float* xb = x + ((size_t)b * CDIM) * HW + hw0;
    float* ob = out + ((size_t)b * CDIM) * HW + hw0;
    double s = 0.0;
    for (int it = 0; it < 16; ++it) {
        int c  = it * 16 + (tid >> 4);
        int m4 = (tid & 15) * 4;
        float4 ev;
        ev.x = sE[m4 + 0][c]; ev.y = sE[m4 + 1][c];
        ev.z = sE[m4 + 2][c]; ev.w = sE[m4 + 3][c];
        float4 xv = *(const float4*)(xb + (size_t)c * HW + m4);
        *(float4*)(ob + (size_t)c * HW + m4) = ev;
        float d0 = ev.x - xv.x, d1 = ev.y - xv.y, d2 = ev.z - xv.z, d3 = ev.w - xv.w;
        s = fma((double)d0, (double)d0, s);
        s = fma((double)d1, (double)d1, s);
        s = fma((double)d2, (double)d2, s);
        s = fma((double)d3, (double)d3, s);
    }
    red[tid] = s;
    __syncthreads();
    for (int sft = 128; sft > 0; sft >>= 1) {
        if (tid < sft) red[tid] += red[tid + sft];
        __syncthreads();
    }
    if (tid == 0) atomicAdd(loss, red[0]);
}

__global__ void fin_kernel(const double* __restrict__ loss, float* __restrict__ o) {
    *o = (float)(1.25 * (*loss) / (double)TOTAL);
}

extern "C" void kernel_launch(void* const* d_in, const int* in_sizes, int n_in,
                              void* d_out, int out_size, void* d_ws, size_t ws_size,
                              hipStream_t stream) {
    const float* x   = (const float*)d_in[0];
    const float* emb = (const float*)d_in[1];
    float* out = (float*)d_out;
    char*  ws  = (char*)d_ws;

    double* loss    = (double*)ws;
    int*    fb_cnt  = (int*)(ws + 8);
    float*  enf     = (float*)(ws + 64);
    int*    idx     = (int*)(ws + 64 + 4096);
    int*    fb_list = idx + NROWS;

    unsigned short* ehg = (unsigned short*)d_out;   // scratch, overwritten by gather

    float* out_xq   = out;
    float* out_idx  = out + (size_t)TOTAL;
    float* out_loss = out + (size_t)TOTAL + NROWS;

    hipLaunchKernelGGL(prep_kernel,      dim3(NV),           dim3(256), 0, stream,
                       emb, ehg, enf, loss, fb_cnt);
    hipLaunchKernelGGL(gemm_argmin_kernel, dim3(NROWS / 64), dim3(256), 0, stream,
                       x, emb, ehg, enf, idx, fb_list, fb_cnt);
    hipLaunchKernelGGL(fallback_kernel,  dim3(256),          dim3(256), 0, stream,
                       x, emb, enf, idx, fb_list, fb_cnt);
    hipLaunchKernelGGL(gather_kernel,    dim3(NROWS / 64),   dim3(256), 0, stream,
                       x, emb, idx, out_xq, out_idx, loss);
    hipLaunchKernelGGL(fin_kernel,       dim3(1),            dim3(1),   0, stream, loss, out_loss);
}